// Round 1
// baseline (179.956 us; speedup 1.0000x reference)
//
#include <hip/hip_runtime.h>
#include <math.h>

#define MG   2001          // NpointsMesh
#define KH   1001          // k = 0..1000
#define BATCH 16
#define NPTS  1024
#define RW    8
#define TAPS  (2*RW+1)

// workspace layout (float offsets)
#define CTAB_OFF 0         // [MG]
#define DKS_OFF  2048      // [2*KH]
#define F_OFF    4096      // [2*MG]
#define G_OFF    8192      // [BATCH*MG]
#define S_OFF    40960     // [BATCH*2*MG]   total ~105K floats (~420KB)

static __device__ __forceinline__ int wrapM(int m) {
  if (m < 0) m += MG;
  else if (m >= MG) m -= MG;
  return m;
}

// per-point Gaussian taps, identical code in spread & energy kernels
static __device__ __forceinline__ void taps_of(float xv, int& m0, float* w) {
  const double PI = 3.14159265358979323846;
  const double h = 2.0*PI/(double)MG;
  const float tauf = (float)(12.0/((double)MG*(double)MG));
  const float inv4tau = (float)(1.0/(4.0*(double)tauf));
  m0 = (int)floor((double)xv/h + 0.5);
  #pragma unroll
  for (int r = 0; r < TAPS; ++r) {
    double d = (double)xv - (double)(m0 + r - RW)*h;
    float df = (float)d;
    w[r] = __expf(-(df*df)*inv4tau);
  }
}

__global__ void __launch_bounds__(256) k_tables(float* __restrict__ ws,
                         const float* __restrict__ s0p, const float* __restrict__ s1p,
                         const float* __restrict__ a0p, const float* __restrict__ a1p) {
  int idx = blockIdx.x*blockDim.x + threadIdx.x;
  const double PI = 3.14159265358979323846;
  if (idx < MG) {
    ws[CTAB_OFF + idx] = (float)cos(2.0*PI*(double)idx/(double)MG);
  } else if (idx < MG + 2*KH) {
    int t = idx - MG;
    int ch = t / KH;
    int k = t - ch*KH;
    float s  = (ch == 0) ? s0p[0] : s1p[0];
    float a  = (ch == 0) ? a0p[0] : a1p[0];
    float mu = (ch == 0) ? 1.0f : 0.5f;
    double tau = (double)(float)(12.0/((double)MG*(double)MG));
    double mus = (double)(mu*s);
    double kk = (double)k*(double)k;
    double deconv2 = (PI/tau)*exp(2.0*kk*tau);          // deconv(k)^2
    double mult = (double)a*4.0*PI/(kk + mus*mus);      // screened Coulomb
    double C = 1.0/(2.0*PI*(double)MG*(double)MG);      // scale * (1/M ifft norm)
    double v = C*deconv2*mult*((k == 0) ? 1.0 : 2.0);   // 2x for +/-k fold
    ws[DKS_OFF + t] = (float)v;
  }
}

// f_ch[m] = sum_k Dks[ch][k] * cos(2*pi*k*m/M); even in m -> compute m=0..1000
__global__ void __launch_bounds__(256) k_fcomp(float* __restrict__ ws) {
  __shared__ float ct[MG];
  __shared__ float dk[2*KH];
  int tid = threadIdx.x;
  for (int j = tid; j < MG;  j += 256) ct[j] = ws[CTAB_OFF + j];
  for (int j = tid; j < 2*KH; j += 256) dk[j] = ws[DKS_OFF + j];
  __syncthreads();
  int idx = blockIdx.x*256 + tid;
  if (idx >= 2*KH) return;
  int ch = idx / KH;
  int m  = idx - ch*KH;              // 0..1000
  const float* dkc = &dk[ch*KH];
  float acc = 0.f;
  int j = 0;                          // j = (k*m) mod M via increments
  for (int k = 0; k < KH; ++k) {
    acc = fmaf(dkc[k], ct[j], acc);
    j += m; if (j >= MG) j -= MG;
  }
  ws[F_OFF + ch*MG + m] = acc;
  if (m > 0) ws[F_OFF + ch*MG + (MG - m)] = acc;
}

// G_b[m] = sum_n g[b,n,m], one block per batch, LDS-privatized scatter
__global__ void __launch_bounds__(256) k_spread(float* __restrict__ ws,
                                                const float* __restrict__ x) {
  __shared__ float Gs[MG];
  int b = blockIdx.x;
  int tid = threadIdx.x;
  for (int j = tid; j < MG; j += 256) Gs[j] = 0.f;
  __syncthreads();
  for (int n = tid; n < NPTS; n += 256) {
    float xv = x[b*NPTS + n];
    int m0; float w[TAPS];
    taps_of(xv, m0, w);
    #pragma unroll
    for (int r = 0; r < TAPS; ++r)
      atomicAdd(&Gs[wrapM(m0 + r - RW)], w[r]);
  }
  __syncthreads();
  for (int j = tid; j < MG; j += 256) ws[G_OFF + b*MG + j] = Gs[j];
}

// S[b,ch,m] = sum_d f_ch[d] * G_b[(m-d) mod M]; both channels per block
__global__ void __launch_bounds__(128) k_conv(float* __restrict__ ws) {
  __shared__ float Gx[2*MG];        // unwrapped G to avoid mod in inner loop
  __shared__ float f1s[MG + 3];
  __shared__ float f2s[MG + 3];
  int b = blockIdx.y;
  int tid = threadIdx.x;
  const float* Gg = &ws[G_OFF + b*MG];
  for (int j = tid; j < 2*MG; j += 128) Gx[j] = Gg[(j < MG) ? j : j - MG];
  for (int j = tid; j < MG; j += 128) {
    f1s[j] = ws[F_OFF + j];
    f2s[j] = ws[F_OFF + MG + j];
  }
  if (tid < 3) { f1s[MG + tid] = 0.f; f2s[MG + tid] = 0.f; }
  __syncthreads();
  int m = blockIdx.x*128 + tid;
  if (m >= MG) return;
  float a1 = 0.f, a2 = 0.f;
  int idx = m + MG;                  // (m - d + M), d=0
  #pragma unroll 4
  for (int d = 0; d < MG; ++d) {
    float gv = Gx[idx--];
    a1 = fmaf(f1s[d], gv, a1);
    a2 = fmaf(f2s[d], gv, a2);
  }
  ws[S_OFF + (b*2 + 0)*MG + m] = a1;
  ws[S_OFF + (b*2 + 1)*MG + m] = a2;
}

// e[b,n,ch] = sum_r w_r*S[b,ch,m0+r] - sum_{r,r'} w_r w_r' f_ch[|r-r'|]
__global__ void __launch_bounds__(256) k_energy(const float* __restrict__ ws,
                                                const float* __restrict__ x,
                                                float* __restrict__ out) {
  int gid = blockIdx.x*256 + threadIdx.x;
  if (gid >= BATCH*NPTS) return;
  int b = gid >> 10;
  float xv = x[gid];
  int m0; float w[TAPS];
  taps_of(xv, m0, w);
  const float* f1 = &ws[F_OFF];
  const float* f2 = &ws[F_OFF + MG];
  const float* S1 = &ws[S_OFF + (b*2 + 0)*MG];
  const float* S2 = &ws[S_OFF + (b*2 + 1)*MG];
  float c1 = 0.f, c2 = 0.f;
  #pragma unroll
  for (int r = 0; r < TAPS; ++r) {
    int mw = wrapM(m0 + r - RW);
    c1 = fmaf(w[r], S1[mw], c1);
    c2 = fmaf(w[r], S2[mw], c2);
  }
  float s1 = 0.f, s2 = 0.f;
  #pragma unroll
  for (int dl = 0; dl <= 2*RW; ++dl) {
    float c = 0.f;
    #pragma unroll
    for (int r = 0; r + dl < TAPS; ++r) c = fmaf(w[r], w[r + dl], c);
    float fac = (dl == 0) ? 1.f : 2.f;
    s1 = fmaf(fac*c, f1[dl], s1);
    s2 = fmaf(fac*c, f2[dl], s2);
  }
  out[gid*2 + 0] = c1 - s1;
  out[gid*2 + 1] = c2 - s2;
}

extern "C" void kernel_launch(void* const* d_in, const int* in_sizes, int n_in,
                              void* d_out, int out_size, void* d_ws, size_t ws_size,
                              hipStream_t stream) {
  const float* x  = (const float*)d_in[0];
  const float* s0 = (const float*)d_in[1];
  const float* s1 = (const float*)d_in[2];
  const float* a0 = (const float*)d_in[3];
  const float* a1 = (const float*)d_in[4];
  float* ws  = (float*)d_ws;
  float* out = (float*)d_out;

  hipLaunchKernelGGL(k_tables, dim3(16), dim3(256), 0, stream, ws, s0, s1, a0, a1);
  hipLaunchKernelGGL(k_fcomp,  dim3(8),  dim3(256), 0, stream, ws);
  hipLaunchKernelGGL(k_spread, dim3(BATCH), dim3(256), 0, stream, ws, x);
  hipLaunchKernelGGL(k_conv,   dim3(16, BATCH), dim3(128), 0, stream, ws);
  hipLaunchKernelGGL(k_energy, dim3((BATCH*NPTS + 255)/256), dim3(256), 0, stream, ws, x, out);
}

// Round 2
// 95.302 us; speedup vs baseline: 1.8883x; 1.8883x over previous
//
#include <hip/hip_runtime.h>
#include <math.h>

#define MG   2001          // NpointsMesh
#define KH   1001          // k = 0..1000
#define BATCH 16
#define NPTS  1024
#define RW    8
#define TAPS  (2*RW+1)

#define DSPLIT 8
#define DCHUNK 251         // 8*251 = 2008 >= 2001
#define KSPLIT 8
#define KCH    126         // 8*126 = 1008 >= 1001
#define PSPLIT 4

// workspace layout (float offsets)
#define CTAB_OFF 0         // [2048]
#define DKS_OFF  2048      // [2][1024]
#define F_OFF    4096      // [2][2048]   (zeroed, atomic-accumulated)
#define G_OFF    8192      // [16][2048]  (zeroed, atomic-accumulated)
#define S_OFF    40960     // [16][2][2048] (zeroed, atomic-accumulated)
#define WS_END   106496

static __device__ __forceinline__ int wrapM(int m) {
  if (m < 0) m += MG;
  else if (m >= MG) m -= MG;
  return m;
}

static __device__ __forceinline__ void taps_of(float xv, int& m0, float* w) {
  const double PI = 3.14159265358979323846;
  const double h = 2.0*PI/(double)MG;
  const float tauf = (float)(12.0/((double)MG*(double)MG));
  const float inv4tau = (float)(1.0/(4.0*(double)tauf));
  m0 = (int)floor((double)xv/h + 0.5);
  #pragma unroll
  for (int r = 0; r < TAPS; ++r) {
    double d = (double)xv - (double)(m0 + r - RW)*h;
    float df = (float)d;
    w[r] = __expf(-(df*df)*inv4tau);
  }
}

__global__ void __launch_bounds__(256) k_tables(float* __restrict__ ws,
                         const float* __restrict__ s0p, const float* __restrict__ s1p,
                         const float* __restrict__ a0p, const float* __restrict__ a1p) {
  int idx = blockIdx.x*blockDim.x + threadIdx.x;
  const double PI = 3.14159265358979323846;
  if (idx < MG) {
    ws[CTAB_OFF + idx] = (float)cos(2.0*PI*(double)idx/(double)MG);
  } else if (idx < MG + 2*KH) {
    int t = idx - MG;
    int ch = t / KH;
    int k = t - ch*KH;
    float s  = (ch == 0) ? s0p[0] : s1p[0];
    float a  = (ch == 0) ? a0p[0] : a1p[0];
    float mu = (ch == 0) ? 1.0f : 0.5f;
    double tau = (double)(float)(12.0/((double)MG*(double)MG));
    double mus = (double)(mu*s);
    double kk = (double)k*(double)k;
    double deconv2 = (PI/tau)*exp(2.0*kk*tau);
    double mult = (double)a*4.0*PI/(kk + mus*mus);
    double C = 1.0/(2.0*PI*(double)MG*(double)MG);
    double v = C*deconv2*mult*((k == 0) ? 1.0 : 2.0);
    ws[DKS_OFF + ch*1024 + k] = (float)v;
  }
}

// f[ch][m] = sum_k dk[ch][k]*cos(2*pi*k*m/M), k-split across blocks, atomic reduce
__global__ void __launch_bounds__(256) k_fcomp(float* __restrict__ ws) {
  __shared__ float ct[2048];
  __shared__ float dkc[128];
  int tid = threadIdx.x;
  int bx = blockIdx.x;
  int mb = bx & 7;
  int ch = (bx >> 3) & 1;
  int ks = bx >> 4;
  int k0 = ks*KCH;
  for (int j = tid; j < MG; j += 256) ct[j] = ws[CTAB_OFF + j];
  if (tid < 128) {
    int k = k0 + tid;
    dkc[tid] = (tid < KCH && k < KH) ? ws[DKS_OFF + ch*1024 + k] : 0.f;
  }
  __syncthreads();
  int m = mb*256 + tid;
  if (m >= MG) return;
  int j = (int)(((long long)k0*(long long)m) % MG);
  float acc = 0.f;
  #pragma unroll 4
  for (int kk = 0; kk < 128; ++kk) {
    acc = fmaf(dkc[kk], ct[j], acc);
    j += m; if (j >= MG) j -= MG;
  }
  atomicAdd(&ws[F_OFF + ch*2048 + m], acc);
}

// G_b[m] = sum_n g[b,n,m]; point-split across PSPLIT blocks per batch
__global__ void __launch_bounds__(256) k_spread(float* __restrict__ ws,
                                                const float* __restrict__ x) {
  __shared__ float Gs[MG];
  int b = blockIdx.x >> 2;
  int psp = blockIdx.x & 3;
  int tid = threadIdx.x;
  for (int j = tid; j < MG; j += 256) Gs[j] = 0.f;
  __syncthreads();
  int n = psp*256 + tid;
  float xv = x[b*NPTS + n];
  int m0; float w[TAPS];
  taps_of(xv, m0, w);
  #pragma unroll
  for (int r = 0; r < TAPS; ++r)
    atomicAdd(&Gs[wrapM(m0 + r - RW)], w[r]);
  __syncthreads();
  float* Gg = &ws[G_OFF + b*2048];
  for (int j = tid; j < MG; j += 256) atomicAdd(&Gg[j], Gs[j]);
}

// S[b,ch,m] = sum_d f_ch[d]*G_b[(m-d) mod M]
// d-split across DSPLIT blocks; each thread computes 4 consecutive m via a
// rolling 8-float window: per 4-d group = 1 ds_read_b128 (G) + 2 b128 (f) + 32 FMA
__global__ void __launch_bounds__(256) k_conv(float* __restrict__ ws) {
  __shared__ __align__(16) float GW[1280];
  __shared__ __align__(16) float FW1[256];
  __shared__ __align__(16) float FW2[256];
  int tid = threadIdx.x;
  int b = blockIdx.y;
  int mb = blockIdx.x & 1;
  int dsp = blockIdx.x >> 1;
  int m0 = mb*1024;
  int d0 = dsp*DCHUNK;

  // stage G window: GW[i] = G[(base+i) mod MG], base = m0 + MG - d0 - 256
  int base = m0 + MG - d0 - 256;
  int baseP = ((base % MG) + MG) % MG;
  const float* Gg = &ws[G_OFF + b*2048];
  for (int i = tid; i < 1280; i += 256) {
    int idx = baseP + i;
    if (idx >= MG) idx -= MG;
    if (idx >= MG) idx -= MG;
    GW[i] = Gg[idx];
  }
  {
    int dd = d0 + tid;
    bool ok = (tid < DCHUNK) && (dd < MG);
    FW1[tid] = ok ? ws[F_OFF + dd] : 0.f;
    FW2[tid] = ok ? ws[F_OFF + 2048 + dd] : 0.f;
  }
  __syncthreads();

  const float4* GW4 = reinterpret_cast<const float4*>(GW);
  const float4* F14 = reinterpret_cast<const float4*>(FW1);
  const float4* F24 = reinterpret_cast<const float4*>(FW2);

  float4 prev = GW4[tid + 64];      // positions p..p+3, p = 4*tid + 256
  float acc1[4] = {0.f,0.f,0.f,0.f};
  float acc2[4] = {0.f,0.f,0.f,0.f};

  #pragma unroll 2
  for (int t = 0; t < 64; ++t) {
    float4 nv = GW4[tid + 63 - t];  // positions p-4..p-1
    float4 f1 = F14[t];
    float4 f2 = F24[t];
    const float pw[4] = {prev.x, prev.y, prev.z, prev.w};
    const float nw[4] = {nv.x, nv.y, nv.z, nv.w};
    const float fj1[4] = {f1.x, f1.y, f1.z, f1.w};
    const float fj2[4] = {f2.x, f2.y, f2.z, f2.w};
    #pragma unroll
    for (int j = 0; j < 4; ++j) {
      #pragma unroll
      for (int s = 0; s < 4; ++s) {
        float w = (s >= j) ? pw[s-j] : nw[4+s-j];
        acc1[s] = fmaf(fj1[j], w, acc1[s]);
        acc2[s] = fmaf(fj2[j], w, acc2[s]);
      }
    }
    prev = nv;
  }

  float* S1 = &ws[S_OFF + (b*2 + 0)*2048];
  float* S2 = &ws[S_OFF + (b*2 + 1)*2048];
  #pragma unroll
  for (int s = 0; s < 4; ++s) {
    int m = m0 + 4*tid + s;
    if (m < MG) {
      atomicAdd(&S1[m], acc1[s]);
      atomicAdd(&S2[m], acc2[s]);
    }
  }
}

__global__ void __launch_bounds__(256) k_energy(const float* __restrict__ ws,
                                                const float* __restrict__ x,
                                                float* __restrict__ out) {
  int gid = blockIdx.x*256 + threadIdx.x;
  if (gid >= BATCH*NPTS) return;
  int b = gid >> 10;
  float xv = x[gid];
  int m0; float w[TAPS];
  taps_of(xv, m0, w);
  const float* f1 = &ws[F_OFF];
  const float* f2 = &ws[F_OFF + 2048];
  const float* S1 = &ws[S_OFF + (b*2 + 0)*2048];
  const float* S2 = &ws[S_OFF + (b*2 + 1)*2048];
  float c1 = 0.f, c2 = 0.f;
  #pragma unroll
  for (int r = 0; r < TAPS; ++r) {
    int mw = wrapM(m0 + r - RW);
    c1 = fmaf(w[r], S1[mw], c1);
    c2 = fmaf(w[r], S2[mw], c2);
  }
  float s1 = 0.f, s2 = 0.f;
  #pragma unroll
  for (int dl = 0; dl <= 2*RW; ++dl) {
    float c = 0.f;
    #pragma unroll
    for (int r = 0; r + dl < TAPS; ++r) c = fmaf(w[r], w[r + dl], c);
    float fac = (dl == 0) ? 1.f : 2.f;
    s1 = fmaf(fac*c, f1[dl], s1);
    s2 = fmaf(fac*c, f2[dl], s2);
  }
  out[gid*2 + 0] = c1 - s1;
  out[gid*2 + 1] = c2 - s2;
}

extern "C" void kernel_launch(void* const* d_in, const int* in_sizes, int n_in,
                              void* d_out, int out_size, void* d_ws, size_t ws_size,
                              hipStream_t stream) {
  const float* x  = (const float*)d_in[0];
  const float* s0 = (const float*)d_in[1];
  const float* s1 = (const float*)d_in[2];
  const float* a0 = (const float*)d_in[3];
  const float* a1 = (const float*)d_in[4];
  float* ws  = (float*)d_ws;
  float* out = (float*)d_out;

  // zero the atomic-accumulated regions (F, G, S)
  hipMemsetAsync((char*)d_ws + (size_t)F_OFF*4, 0, (size_t)(WS_END - F_OFF)*4, stream);

  hipLaunchKernelGGL(k_tables, dim3(16), dim3(256), 0, stream, ws, s0, s1, a0, a1);
  hipLaunchKernelGGL(k_spread, dim3(BATCH*PSPLIT), dim3(256), 0, stream, ws, x);
  hipLaunchKernelGGL(k_fcomp,  dim3(128), dim3(256), 0, stream, ws);
  hipLaunchKernelGGL(k_conv,   dim3(2*DSPLIT, BATCH), dim3(256), 0, stream, ws);
  hipLaunchKernelGGL(k_energy, dim3((BATCH*NPTS + 255)/256), dim3(256), 0, stream, ws, x, out);
}